// Round 2
// 650.071 us; speedup vs baseline: 1.0493x; 1.0493x over previous
//
#include <hip/hip_runtime.h>
#include <math.h>

#define LL 8
#define KK 8
#define NN 1048576
#define CHUNKS 256               // gram-partial chunks per layer (2048 blocks -> better latency hiding)
#define CHUNK_N (NN / CHUNKS)    // 4096 n per chunk
#define NPAIR 36                 // triangular 8x8 pairs

typedef float vfloat4 __attribute__((ext_vector_type(4)));

__host__ __device__ constexpr int tri_idx(int k, int j) {
    // k <= j
    return k * 8 - (k * (k - 1)) / 2 + (j - k);
}

// Kernel 1: per-(layer, chunk) partial Gram sums, 36 triangular pairs.
// Plain (caching) loads on purpose: this pass pulls all of deltas (256 MiB)
// into Infinity Cache so kernel 3 can re-read it from L3 instead of HBM.
__global__ __launch_bounds__(256) void gram_partial(const float* __restrict__ deltas,
                                                    float* __restrict__ partials) {
    const int l = blockIdx.y;
    const int c = blockIdx.x;
    const int t = threadIdx.x;
    const float* dl = deltas + (size_t)l * KK * NN;
    const int n0 = c * CHUNK_N;

    float acc[NPAIR];
#pragma unroll
    for (int p = 0; p < NPAIR; ++p) acc[p] = 0.f;

    // CHUNK_N / (256 threads * 4 floats) = 4 iterations
    for (int it = 0; it < CHUNK_N / (256 * 4); ++it) {
        const int n = n0 + (it * 256 + t) * 4;
        vfloat4 d[8];
#pragma unroll
        for (int j = 0; j < 8; ++j)
            d[j] = *(const vfloat4*)(dl + (size_t)j * NN + n);
#pragma unroll
        for (int k = 0; k < 8; ++k) {
#pragma unroll
            for (int j = k; j < 8; ++j) {
                const int p = tri_idx(k, j);
                vfloat4 m = d[k] * d[j];
                acc[p] += m.x + m.y + m.z + m.w;
            }
        }
    }

    // wave(64) shuffle reduce, then cross-wave via LDS
    __shared__ float red[4][NPAIR];
    const int lane = t & 63, wave = t >> 6;
#pragma unroll
    for (int p = 0; p < NPAIR; ++p) {
        float v = acc[p];
#pragma unroll
        for (int off = 32; off > 0; off >>= 1) v += __shfl_down(v, off, 64);
        if (lane == 0) red[wave][p] = v;
    }
    __syncthreads();
    if (t < NPAIR) {
        const float v = red[0][t] + red[1][t] + red[2][t] + red[3][t];
        partials[((size_t)(l * CHUNKS + c)) * NPAIR + t] = v;
    }
}

// Kernel 2: reduce chunk partials, softmax rows, fold clip(beta) -> w[l,k,j]
__global__ __launch_bounds__(64) void softmax_w(const float* __restrict__ partials,
                                                const float* __restrict__ beta,
                                                float* __restrict__ wcoef) {
    const int l = blockIdx.x;
    const int t = threadIdx.x;        // t = k*8 + j
    const int k = t >> 3, j = t & 7;
    const int a = k < j ? k : j, b2 = k < j ? j : k;
    const int p = a * 8 - (a * (a - 1)) / 2 + (b2 - a);
    float g = 0.f;
    for (int c = 0; c < CHUNKS; ++c)
        g += partials[((size_t)(l * CHUNKS + c)) * NPAIR + p];
    __shared__ float gs[64];
    __shared__ float w[64];
    gs[t] = g * 0.0009765625f;        // * N^-0.5 = 1/1024
    __syncthreads();
    if (t < 8) {
        float m = -INFINITY;
        for (int q = 0; q < 8; ++q) m = fmaxf(m, gs[t * 8 + q]);
        float e[8], s = 0.f;
        for (int q = 0; q < 8; ++q) { e[q] = expf(gs[t * 8 + q] - m); s += e[q]; }
        float b = beta[l * 8 + t];
        b = fminf(fmaxf(b, 0.f), 1.f);
        const float inv = b / s;
        for (int q = 0; q < 8; ++q) w[t * 8 + q] = e[q] * inv;
    }
    __syncthreads();
    wcoef[(size_t)l * 64 + t] = w[t];
}

// Kernel 3: out[l,k,n] = last + deltas[k] + sum_j w[k,j]*deltas[j]
// deltas: plain loads (should hit Infinity Cache, populated by kernel 1).
// last:   nontemporal loads  (zero reuse -> don't evict deltas from L3).
// out:    nontemporal stores (zero reuse -> don't dirty/evict L3).
__global__ __launch_bounds__(256) void apply_out(const float* __restrict__ last,
                                                 const float* __restrict__ deltas,
                                                 const float* __restrict__ wcoef,
                                                 float* __restrict__ out) {
    const int l = blockIdx.y;
    const int t = threadIdx.x;
    __shared__ float w[64];
    if (t < 64) w[t] = wcoef[(size_t)l * 64 + t];
    __syncthreads();
    const int n = (blockIdx.x * 256 + t) * 4;
    const float* dl = deltas + (size_t)l * KK * NN;
    const float* lp = last + (size_t)l * KK * NN;
    float* ol = out + (size_t)l * KK * NN;
    vfloat4 d[8];
#pragma unroll
    for (int j = 0; j < 8; ++j)
        d[j] = *(const vfloat4*)(dl + (size_t)j * NN + n);
#pragma unroll
    for (int k = 0; k < 8; ++k) {
        vfloat4 o = __builtin_nontemporal_load((const vfloat4*)(lp + (size_t)k * NN + n));
        o += d[k];
#pragma unroll
        for (int j = 0; j < 8; ++j) {
            const float wk = w[k * 8 + j];
            o += wk * d[j];
        }
        __builtin_nontemporal_store(o, (vfloat4*)(ol + (size_t)k * NN + n));
    }
}

extern "C" void kernel_launch(void* const* d_in, const int* in_sizes, int n_in,
                              void* d_out, int out_size, void* d_ws, size_t ws_size,
                              hipStream_t stream) {
    const float* last   = (const float*)d_in[0];
    const float* deltas = (const float*)d_in[1];
    const float* beta   = (const float*)d_in[2];
    float* out = (float*)d_out;

    float* partials = (float*)d_ws;                               // L*CHUNKS*36 floats (~295 KB)
    float* wcoef    = partials + (size_t)LL * CHUNKS * NPAIR;     // L*64 floats

    gram_partial<<<dim3(CHUNKS, LL), 256, 0, stream>>>(deltas, partials);
    softmax_w<<<LL, 64, 0, stream>>>(partials, beta, wcoef);
    apply_out<<<dim3(NN / 1024, LL), 256, 0, stream>>>(last, deltas, wcoef, out);
}